// Round 2
// baseline (475.896 us; speedup 1.0000x reference)
//
#include <hip/hip_runtime.h>
#include <hip/hip_bf16.h>

#define HW   4096
#define HW4  1024
#define EPS  1e-5f

// ---------------------------------------------------------------------------
// Kernel A: branches 1-3 fused conv1x1 + BN + ReLU. fp32 in/out.
// Y[b][j][p], j<192: j<32 -> branch1 (f pre-pool), 32<=j<64 -> branch2 (g),
// 64<=j<192 -> branch3 (h pre-pool). GEMM tile 64oc x 64p, K=256.
// ---------------------------------------------------------------------------
__global__ __launch_bounds__(256) void conv123_kernel(
    const float* __restrict__ x,
    const float* __restrict__ w1, const float* __restrict__ b1, const float* __restrict__ s1,
    const float* __restrict__ t1, const float* __restrict__ m1, const float* __restrict__ v1,
    const float* __restrict__ w2, const float* __restrict__ b2, const float* __restrict__ s2,
    const float* __restrict__ t2, const float* __restrict__ m2, const float* __restrict__ v2,
    const float* __restrict__ w3, const float* __restrict__ b3, const float* __restrict__ s3,
    const float* __restrict__ t3, const float* __restrict__ m3, const float* __restrict__ v3,
    float* __restrict__ y192)
{
    __shared__ float Ws[64][65];
    __shared__ float Xs[64][65];
    const int t  = threadIdx.x;
    const int tx = t & 15, ty = t >> 4;
    const int bz = blockIdx.z;
    const int ocBase = blockIdx.y * 64;
    const int pBase  = blockIdx.x * 64;

    float acc[4][4] = {};
    for (int k0 = 0; k0 < 256; k0 += 64) {
        #pragma unroll 4
        for (int i = 0; i < 16; ++i) {
            int l = t + i * 256;
            int oc = l >> 6, kk = l & 63;
            int j = ocBase + oc;
            int k = k0 + kk;
            float wv;
            if (j < 32)       wv = w1[j * 256 + k];
            else if (j < 64)  wv = w2[(j - 32) * 256 + k];
            else              wv = w3[(j - 64) * 256 + k];
            Ws[oc][kk] = wv;
        }
        #pragma unroll 4
        for (int i = 0; i < 16; ++i) {
            int l = t + i * 256;
            int kk = l >> 6, pp = l & 63;
            Xs[kk][pp] = x[((size_t)bz * 256 + (k0 + kk)) * HW + pBase + pp];
        }
        __syncthreads();
        #pragma unroll 8
        for (int kk = 0; kk < 64; ++kk) {
            float av[4], xv[4];
            #pragma unroll
            for (int i = 0; i < 4; ++i) av[i] = Ws[ty * 4 + i][kk];
            #pragma unroll
            for (int j = 0; j < 4; ++j) xv[j] = Xs[kk][tx * 4 + j];
            #pragma unroll
            for (int i = 0; i < 4; ++i)
                #pragma unroll
                for (int j = 0; j < 4; ++j)
                    acc[i][j] += av[i] * xv[j];
        }
        __syncthreads();
    }

    #pragma unroll
    for (int i = 0; i < 4; ++i) {
        int j = ocBase + ty * 4 + i;
        float pb, psc, pt, pm, pv;
        if (j < 32)      { pb=b1[j];    psc=s1[j];    pt=t1[j];    pm=m1[j];    pv=v1[j]; }
        else if (j < 64) { int c=j-32; pb=b2[c]; psc=s2[c]; pt=t2[c]; pm=m2[c]; pv=v2[c]; }
        else             { int c=j-64; pb=b3[c]; psc=s3[c]; pt=t3[c]; pm=m3[c]; pv=v3[c]; }
        float alpha = psc * rsqrtf(pv + EPS);
        float beta  = (pb - pm) * alpha + pt;
        #pragma unroll
        for (int jj = 0; jj < 4; ++jj) {
            float y = fmaxf(acc[i][jj] * alpha + beta, 0.f);
            y192[((size_t)bz * 192 + j) * HW + pBase + tx * 4 + jj] = y;
        }
    }
}

// ---------------------------------------------------------------------------
// Kernel B: 2x2 maxpool of f-rows (j 0..32) -> fbuf[8][32][1024] and
// h-rows (j 64..192) -> hhbuf[8][128][1024].
// ---------------------------------------------------------------------------
__global__ __launch_bounds__(256) void pool_kernel(
    const float* __restrict__ y192, float* __restrict__ fbuf, float* __restrict__ hhbuf)
{
    int t  = blockIdx.x * 256 + threadIdx.x;   // 8*160*1024 total
    int n  = t & 1023;
    int ch = (t >> 10) % 160;
    int bz = t / (1024 * 160);
    int ph = n >> 5, pw = n & 31;
    int j = (ch < 32) ? ch : (ch + 32);
    const float* src = y192 + ((size_t)bz * 192 + j) * HW + (ph * 2) * 64 + pw * 2;
    float v00 = src[0], v01 = src[1], v10 = src[64], v11 = src[65];
    float mx = fmaxf(fmaxf(v00, v01), fmaxf(v10, v11));
    if (ch < 32) fbuf[((size_t)bz * 32 + ch) * HW4 + n]          = mx;
    else         hhbuf[((size_t)bz * 128 + (ch - 32)) * HW4 + n] = mx;
}

// ---------------------------------------------------------------------------
// Kernel C: fused flash-style attention. Per block: one batch, 64 m-columns.
// s[n,m] = sum_k f[k,n] g[k,m]; beta = softmax over n (1024, 16 tiles of 64);
// o[c,m] = sum_n hh[c,n] beta[n,m]. o stored transposed: obuf[b][m][c].
// ---------------------------------------------------------------------------
__global__ __launch_bounds__(256) void attn_kernel(
    const float* __restrict__ y192,   // g = rows 32..64
    const float* __restrict__ fbuf,   // [8][32][1024]
    const float* __restrict__ hhbuf,  // [8][128][1024]
    float* __restrict__ obuf)         // [8][4096][128]
{
    __shared__ __align__(16) float gT[32][64];
    __shared__ float hhLds[128][65];
    __shared__ __align__(16) float sTile[64][68];
    __shared__ float red[4][64];
    __shared__ float runmax[64], runsum[64], alphaL[64], newmaxL[64];

    const int t  = threadIdx.x;
    const int bz = blockIdx.y;
    const int m0 = blockIdx.x * 64;

    // load g tile once (32 k x 64 m)
    #pragma unroll
    for (int i = 0; i < 8; ++i) {
        int l = t + i * 256;
        int k = l >> 6, m = l & 63;
        gT[k][m] = y192[((size_t)bz * 192 + 32 + k) * HW + m0 + m];
    }
    if (t < 64) { runmax[t] = -1e30f; runsum[t] = 0.f; }

    const int snj = t & 63,  smi = t >> 6;     // s-compute mapping
    const int rm  = t & 63,  rseg = t >> 6;    // reduce/exp mapping
    const int oc_ = t & 127, omg = t >> 7;     // o-update mapping
    float oacc[32] = {};

    const float* fcolBase = fbuf + (size_t)bz * 32 * HW4;

    for (int n0 = 0; n0 < 1024; n0 += 64) {
        __syncthreads();
        // load hh tile (128 c x 64 nj)
        #pragma unroll 4
        for (int i = 0; i < 32; ++i) {
            int l = t + i * 256;
            int c = l >> 6, nj = l & 63;
            hhLds[c][nj] = hhbuf[((size_t)bz * 128 + c) * HW4 + n0 + nj];
        }
        __syncthreads();

        // s compute: thread owns s[snj][smi*16 .. +16]
        float sacc[16] = {};
        const float* fcol = fcolBase + n0 + snj;
        #pragma unroll 4
        for (int k = 0; k < 32; ++k) {
            float fv = fcol[k * HW4];
            const float4* g4 = (const float4*)(&gT[k][smi * 16]);
            float4 ga = g4[0], gb = g4[1], gc = g4[2], gd = g4[3];
            sacc[0]  += fv * ga.x; sacc[1]  += fv * ga.y; sacc[2]  += fv * ga.z; sacc[3]  += fv * ga.w;
            sacc[4]  += fv * gb.x; sacc[5]  += fv * gb.y; sacc[6]  += fv * gb.z; sacc[7]  += fv * gb.w;
            sacc[8]  += fv * gc.x; sacc[9]  += fv * gc.y; sacc[10] += fv * gc.z; sacc[11] += fv * gc.w;
            sacc[12] += fv * gd.x; sacc[13] += fv * gd.y; sacc[14] += fv * gd.z; sacc[15] += fv * gd.w;
        }
        #pragma unroll
        for (int q = 0; q < 16; ++q) sTile[snj][smi * 16 + q] = sacc[q];
        __syncthreads();

        // tile max per m (4-way partial over nj segments)
        float lmax = -1e30f;
        #pragma unroll
        for (int q = 0; q < 16; ++q) lmax = fmaxf(lmax, sTile[rseg * 16 + q][rm]);
        red[rseg][rm] = lmax;
        __syncthreads();
        if (t < 64) {
            float tm = fmaxf(fmaxf(red[0][t], red[1][t]), fmaxf(red[2][t], red[3][t]));
            float nm = fmaxf(runmax[t], tm);
            alphaL[t]  = __expf(runmax[t] - nm);
            runmax[t]  = nm;
            newmaxL[t] = nm;
        }
        __syncthreads();

        // exp in place + partial sums
        {
            float nm = newmaxL[rm];
            float psum = 0.f;
            #pragma unroll
            for (int q = 0; q < 16; ++q) {
                int nj = rseg * 16 + q;
                float e = __expf(sTile[nj][rm] - nm);
                sTile[nj][rm] = e;
                psum += e;
            }
            red[rseg][rm] = psum;
        }
        __syncthreads();
        if (t < 64)
            runsum[t] = runsum[t] * alphaL[t] + (red[0][t] + red[1][t] + red[2][t] + red[3][t]);

        // o update: thread owns c=oc_, m = m0 + omg*32 .. +32
        #pragma unroll
        for (int q = 0; q < 32; ++q) oacc[q] *= alphaL[omg * 32 + q];
        for (int nj = 0; nj < 64; ++nj) {
            float hv = hhLds[oc_][nj];
            const float4* s4p = (const float4*)(&sTile[nj][omg * 32]);
            #pragma unroll
            for (int q = 0; q < 8; ++q) {
                float4 sv = s4p[q];
                oacc[4*q+0] += hv * sv.x; oacc[4*q+1] += hv * sv.y;
                oacc[4*q+2] += hv * sv.z; oacc[4*q+3] += hv * sv.w;
            }
        }
    }
    __syncthreads();

    #pragma unroll
    for (int q = 0; q < 32; ++q) {
        float inv = 1.0f / runsum[omg * 32 + q];
        obuf[((size_t)bz * HW + (m0 + omg * 32 + q)) * 128 + oc_] = oacc[q] * inv;
    }
}

// ---------------------------------------------------------------------------
// Kernel D: final conv1x1 (256<-128) + BN (no relu), out = gamma*y + x.
// obuf layout [b][m][c] so K-dim loads are coalesced.
// ---------------------------------------------------------------------------
__global__ __launch_bounds__(256) void conv4_kernel(
    const float* __restrict__ obuf,
    const float* __restrict__ x,
    const float* __restrict__ w4, const float* __restrict__ b4, const float* __restrict__ s4,
    const float* __restrict__ t4, const float* __restrict__ m4, const float* __restrict__ v4,
    const float* __restrict__ gamma, float* __restrict__ out)
{
    __shared__ float Ws[64][65];
    __shared__ float Xs[64][65];
    const int t  = threadIdx.x;
    const int tx = t & 15, ty = t >> 4;
    const int bz = blockIdx.z;
    const int ocBase = blockIdx.y * 64;
    const int pBase  = blockIdx.x * 64;

    float acc[4][4] = {};
    for (int k0 = 0; k0 < 128; k0 += 64) {
        #pragma unroll 4
        for (int i = 0; i < 16; ++i) {
            int l = t + i * 256;
            int oc = l >> 6, kk = l & 63;
            Ws[oc][kk] = w4[(ocBase + oc) * 128 + k0 + kk];
        }
        #pragma unroll 4
        for (int i = 0; i < 16; ++i) {
            int l = t + i * 256;
            int kk = l & 63, pp = l >> 6;
            Xs[kk][pp] = obuf[((size_t)bz * HW + pBase + pp) * 128 + k0 + kk];
        }
        __syncthreads();
        #pragma unroll 8
        for (int kk = 0; kk < 64; ++kk) {
            float av[4], xv[4];
            #pragma unroll
            for (int i = 0; i < 4; ++i) av[i] = Ws[ty * 4 + i][kk];
            #pragma unroll
            for (int j = 0; j < 4; ++j) xv[j] = Xs[kk][tx * 4 + j];
            #pragma unroll
            for (int i = 0; i < 4; ++i)
                #pragma unroll
                for (int j = 0; j < 4; ++j)
                    acc[i][j] += av[i] * xv[j];
        }
        __syncthreads();
    }

    float gm = gamma[0];
    #pragma unroll
    for (int i = 0; i < 4; ++i) {
        int oc = ocBase + ty * 4 + i;
        float pb = b4[oc], psc = s4[oc], pt = t4[oc];
        float pm = m4[oc], pv = v4[oc];
        float alpha = psc * rsqrtf(pv + EPS);
        float beta  = (pb - pm) * alpha + pt;
        #pragma unroll
        for (int jj = 0; jj < 4; ++jj) {
            int p = pBase + tx * 4 + jj;
            float y  = acc[i][jj] * alpha + beta;
            float xo = x[((size_t)bz * 256 + oc) * HW + p];
            out[((size_t)bz * 256 + oc) * HW + p] = gm * y + xo;
        }
    }
}

extern "C" void kernel_launch(void* const* d_in, const int* in_sizes, int n_in,
                              void* d_out, int out_size, void* d_ws, size_t ws_size,
                              hipStream_t stream)
{
    const float* x  = (const float*)d_in[0];
    const float* w1 = (const float*)d_in[1];
    const float* b1 = (const float*)d_in[2];
    const float* s1 = (const float*)d_in[3];
    const float* t1 = (const float*)d_in[4];
    const float* m1 = (const float*)d_in[5];
    const float* v1 = (const float*)d_in[6];
    const float* w2 = (const float*)d_in[7];
    const float* b2 = (const float*)d_in[8];
    const float* s2 = (const float*)d_in[9];
    const float* t2 = (const float*)d_in[10];
    const float* m2 = (const float*)d_in[11];
    const float* v2 = (const float*)d_in[12];
    const float* w3 = (const float*)d_in[13];
    const float* b3 = (const float*)d_in[14];
    const float* s3 = (const float*)d_in[15];
    const float* t3 = (const float*)d_in[16];
    const float* m3 = (const float*)d_in[17];
    const float* v3 = (const float*)d_in[18];
    const float* w4 = (const float*)d_in[19];
    const float* b4 = (const float*)d_in[20];
    const float* s4 = (const float*)d_in[21];
    const float* t4 = (const float*)d_in[22];
    const float* m4 = (const float*)d_in[23];
    const float* v4 = (const float*)d_in[24];
    const float* gm = (const float*)d_in[25];
    float* out = (float*)d_out;

    float* y192  = (float*)d_ws;                     // 8*192*4096
    float* fbuf  = y192  + (size_t)8 * 192 * 4096;   // 8*32*1024
    float* hhbuf = fbuf  + (size_t)8 * 32 * 1024;    // 8*128*1024
    float* obuf  = hhbuf + (size_t)8 * 128 * 1024;   // 8*4096*128

    conv123_kernel<<<dim3(64, 3, 8), 256, 0, stream>>>(
        x, w1, b1, s1, t1, m1, v1, w2, b2, s2, t2, m2, v2, w3, b3, s3, t3, m3, v3, y192);
    pool_kernel<<<dim3(5120), 256, 0, stream>>>(y192, fbuf, hhbuf);
    attn_kernel<<<dim3(64, 8), 256, 0, stream>>>(y192, fbuf, hhbuf, obuf);
    conv4_kernel<<<dim3(64, 4, 8), 256, 0, stream>>>(
        obuf, x, w4, b4, s4, t4, m4, v4, gm, out);
}

// Round 3
// 184.686 us; speedup vs baseline: 2.5768x; 2.5768x over previous
//
#include <hip/hip_runtime.h>
#include <hip/hip_bf16.h>

#define HW   4096
#define HW4  1024
#define EPS  1e-5f

typedef __attribute__((ext_vector_type(8))) short bf16x8;   // 8 bf16 (4 VGPRs)
typedef __attribute__((ext_vector_type(4))) float f32x4;    // MFMA C/D

__device__ __forceinline__ short f2bs(float f) {            // fp32 -> bf16 bits (RNE)
    union { float f; unsigned u; } v; v.f = f;
    unsigned r = v.u + 0x7FFFu + ((v.u >> 16) & 1u);
    return (short)(r >> 16);
}
__device__ __forceinline__ float bs2f(short s) {
    union { unsigned u; float f; } v; v.u = ((unsigned)(unsigned short)s) << 16;
    return v.f;
}
// XOR-swizzled LDS layouts: 16B chunks permuted by row so b128 fragment reads
// and staging writes stay near conflict-free. Row strides 64/32 shorts.
__device__ __forceinline__ int swz64(int r, int c) { return (r << 6) + ((c ^ (r & 7)) << 3); }
__device__ __forceinline__ int swz32(int r, int c) { return (r << 5) + ((c ^ (r & 3)) << 3); }

// ---------------------------------------------------------------------------
// Kernel A: branches 1-3 conv1x1 + BN + ReLU via MFMA. One block = all 192 oc
// x 64 p for one batch (x tile read once). y192 output in bf16.
// ---------------------------------------------------------------------------
__global__ __launch_bounds__(256) void conv123_mfma(
    const float* __restrict__ x,
    const float* __restrict__ w1, const float* __restrict__ b1, const float* __restrict__ s1,
    const float* __restrict__ t1, const float* __restrict__ m1, const float* __restrict__ v1,
    const float* __restrict__ w2, const float* __restrict__ b2, const float* __restrict__ s2,
    const float* __restrict__ t2, const float* __restrict__ m2, const float* __restrict__ v2,
    const float* __restrict__ w3, const float* __restrict__ b3, const float* __restrict__ s3,
    const float* __restrict__ t3, const float* __restrict__ m3, const float* __restrict__ v3,
    short* __restrict__ y192)
{
    __shared__ __align__(16) short Wl[192 * 64];
    __shared__ __align__(16) short Xl[64 * 64];
    __shared__ float alB[192], beB[192];

    const int t = threadIdx.x;
    const int lane = t & 63, wv = t >> 6;
    const int quad = lane >> 4, l16 = lane & 15;
    const int bz = blockIdx.y;
    const int pBase = blockIdx.x * 64;

    if (t < 192) {
        int j = t;
        float pb, ps, ptv, pm, pv;
        if (j < 32)      { pb = b1[j]; ps = s1[j]; ptv = t1[j]; pm = m1[j]; pv = v1[j]; }
        else if (j < 64) { int c = j - 32; pb = b2[c]; ps = s2[c]; ptv = t2[c]; pm = m2[c]; pv = v2[c]; }
        else             { int c = j - 64; pb = b3[c]; ps = s3[c]; ptv = t3[c]; pm = m3[c]; pv = v3[c]; }
        float al = ps * rsqrtf(pv + EPS);
        alB[j] = al; beB[j] = (pb - pm) * al + ptv;
    }

    const f32x4 fzero = {0.f, 0.f, 0.f, 0.f};
    f32x4 acc[3][4];
    #pragma unroll
    for (int i = 0; i < 3; ++i)
        #pragma unroll
        for (int j = 0; j < 4; ++j) acc[i][j] = fzero;

    for (int k0 = 0; k0 < 256; k0 += 64) {
        // stage Wcat (192 oc x 64 k), fp32 -> bf16, natural [oc][k]
        #pragma unroll
        for (int i = 0; i < 3; ++i) {
            int oc = i * 64 + (t >> 2);
            int kb = (t & 3) * 16;
            const float* wp;
            if (oc < 32)      wp = w1 + oc * 256;
            else if (oc < 64) wp = w2 + (oc - 32) * 256;
            else              wp = w3 + (oc - 64) * 256;
            float4 a = *(const float4*)(wp + k0 + kb);
            float4 b = *(const float4*)(wp + k0 + kb + 4);
            float4 c = *(const float4*)(wp + k0 + kb + 8);
            float4 d = *(const float4*)(wp + k0 + kb + 12);
            bf16x8 lo, hi;
            lo[0]=f2bs(a.x); lo[1]=f2bs(a.y); lo[2]=f2bs(a.z); lo[3]=f2bs(a.w);
            lo[4]=f2bs(b.x); lo[5]=f2bs(b.y); lo[6]=f2bs(b.z); lo[7]=f2bs(b.w);
            hi[0]=f2bs(c.x); hi[1]=f2bs(c.y); hi[2]=f2bs(c.z); hi[3]=f2bs(c.w);
            hi[4]=f2bs(d.x); hi[5]=f2bs(d.y); hi[6]=f2bs(d.z); hi[7]=f2bs(d.w);
            *(bf16x8*)&Wl[swz64(oc, (kb >> 3))]     = lo;
            *(bf16x8*)&Wl[swz64(oc, (kb >> 3) + 1)] = hi;
        }
        // stage X transposed: Xl[p][k]
        {
            int pp = t & 63, k8 = t >> 6;
            float fv[16];
            #pragma unroll
            for (int i = 0; i < 16; ++i)
                fv[i] = x[((size_t)bz * 256 + k0 + k8 * 16 + i) * HW + pBase + pp];
            bf16x8 lo, hi;
            #pragma unroll
            for (int i = 0; i < 8; ++i) { lo[i] = f2bs(fv[i]); hi[i] = f2bs(fv[8 + i]); }
            *(bf16x8*)&Xl[swz64(pp, k8 * 2)]     = lo;
            *(bf16x8*)&Xl[swz64(pp, k8 * 2 + 1)] = hi;
        }
        __syncthreads();
        #pragma unroll
        for (int kk = 0; kk < 2; ++kk) {
            bf16x8 bfr[4];
            #pragma unroll
            for (int pt = 0; pt < 4; ++pt)
                bfr[pt] = *(const bf16x8*)&Xl[swz64(pt * 16 + l16, kk * 4 + quad)];
            #pragma unroll
            for (int tt = 0; tt < 3; ++tt) {
                bf16x8 afr = *(const bf16x8*)&Wl[swz64(wv * 48 + tt * 16 + l16, kk * 4 + quad)];
                #pragma unroll
                for (int pt = 0; pt < 4; ++pt)
                    acc[tt][pt] = __builtin_amdgcn_mfma_f32_16x16x32_bf16(afr, bfr[pt], acc[tt][pt], 0, 0, 0);
            }
        }
        __syncthreads();
    }

    #pragma unroll
    for (int tt = 0; tt < 3; ++tt) {
        #pragma unroll
        for (int r = 0; r < 4; ++r) {
            int oc = wv * 48 + tt * 16 + quad * 4 + r;
            float al = alB[oc], be = beB[oc];
            #pragma unroll
            for (int pt = 0; pt < 4; ++pt) {
                int p = pBase + pt * 16 + l16;
                float y = fmaxf(acc[tt][pt][r] * al + be, 0.f);
                y192[((size_t)bz * 192 + oc) * HW + p] = f2bs(y);
            }
        }
    }
}

// ---------------------------------------------------------------------------
// Kernel B: 2x2 maxpool (bf16 in/out). f-rows 0..32 -> fbuf, h-rows 64..192 -> hhbuf.
// ---------------------------------------------------------------------------
__global__ __launch_bounds__(256) void pool_kernel(
    const short* __restrict__ y192, short* __restrict__ fbuf, short* __restrict__ hhbuf)
{
    int t  = blockIdx.x * 256 + threadIdx.x;
    int n  = t & 1023;
    int ch = (t >> 10) % 160;
    int bz = t / (1024 * 160);
    int ph = n >> 5, pw = n & 31;
    int j = (ch < 32) ? ch : (ch + 32);
    const short* src = y192 + ((size_t)bz * 192 + j) * HW + (ph * 2) * 64 + pw * 2;
    float v00 = bs2f(src[0]), v01 = bs2f(src[1]), v10 = bs2f(src[64]), v11 = bs2f(src[65]);
    float mx = fmaxf(fmaxf(v00, v01), fmaxf(v10, v11));
    short o = f2bs(mx);
    if (ch < 32) fbuf[((size_t)bz * 32 + ch) * HW4 + n]          = o;
    else         hhbuf[((size_t)bz * 128 + (ch - 32)) * HW4 + n] = o;
}

// ---------------------------------------------------------------------------
// Kernel C: fused flash attention, MFMA. Block = (batch, 64-m tile), 4 waves.
// Wave w owns m-strip w*16: computes s (4 n-tiles, K=32), reg-resident online
// softmax (per-lane m stats, shfl across quads), writes beta^T to LDS (own
// rows -> no barrier), accumulates o (128c x 16m) in 8 MFMA tiles.
// ---------------------------------------------------------------------------
__global__ __launch_bounds__(256) void attn_mfma(
    const short* __restrict__ y192,
    const short* __restrict__ fbuf,
    const short* __restrict__ hhbuf,
    short* __restrict__ obuf)
{
    __shared__ __align__(16) short gTl[64 * 32];
    __shared__ __align__(16) short fTl[64 * 32];
    __shared__ __align__(16) short hhl[128 * 64];
    __shared__ __align__(16) short sTl[64 * 64];

    const int t = threadIdx.x;
    const int lane = t & 63, wv = t >> 6;
    const int quad = lane >> 4, l16 = lane & 15;
    const int bz = blockIdx.y;
    const int m0 = blockIdx.x * 64;
    const int ms = wv * 16;
    const f32x4 fzero = {0.f, 0.f, 0.f, 0.f};

    // stage g^T once: gTl[m][k]
    {
        int mm = t & 63, k8 = t >> 6;
        bf16x8 v;
        #pragma unroll
        for (int j = 0; j < 8; ++j)
            v[j] = y192[((size_t)bz * 192 + 32 + k8 * 8 + j) * HW + m0 + mm];
        *(bf16x8*)&gTl[swz32(mm, k8)] = v;
    }
    __syncthreads();
    bf16x8 bg = *(const bf16x8*)&gTl[swz32(ms + l16, quad)];   // loop-invariant B-frag

    float runmax = -1e30f, runsum = 0.f;
    f32x4 oacc[8];
    #pragma unroll
    for (int i = 0; i < 8; ++i) oacc[i] = fzero;

    for (int n0 = 0; n0 < 1024; n0 += 64) {
        __syncthreads();   // prior-iter readers of fTl/hhl done
        // stage f^T: fTl[n][k]
        {
            int nn = t & 63, k8 = t >> 6;
            bf16x8 v;
            #pragma unroll
            for (int j = 0; j < 8; ++j)
                v[j] = fbuf[((size_t)bz * 32 + k8 * 8 + j) * HW4 + n0 + nn];
            *(bf16x8*)&fTl[swz32(nn, k8)] = v;
        }
        // stage hh: hhl[c][n] (natural layout, b128 global reads)
        {
            int c0 = t >> 3, nc = t & 7;
            #pragma unroll
            for (int i = 0; i < 4; ++i) {
                int c = i * 32 + c0;
                bf16x8 v = *(const bf16x8*)(hhbuf + ((size_t)bz * 128 + c) * HW4 + n0 + nc * 8);
                *(bf16x8*)&hhl[swz64(c, nc)] = v;
            }
        }
        __syncthreads();

        // s-phase: s[n][m], wave's 16-m strip, 4 n-tiles
        f32x4 sacc[4];
        #pragma unroll
        for (int nt = 0; nt < 4; ++nt) {
            bf16x8 af = *(const bf16x8*)&fTl[swz32(nt * 16 + l16, quad)];
            sacc[nt] = __builtin_amdgcn_mfma_f32_16x16x32_bf16(af, bg, fzero, 0, 0, 0);
        }

        // online softmax over n (col m = lane&15 -> per-lane scalar stats)
        float tmax = -1e30f;
        #pragma unroll
        for (int nt = 0; nt < 4; ++nt)
            #pragma unroll
            for (int r = 0; r < 4; ++r) tmax = fmaxf(tmax, sacc[nt][r]);
        tmax = fmaxf(tmax, __shfl_xor(tmax, 16));
        tmax = fmaxf(tmax, __shfl_xor(tmax, 32));
        float nmax  = fmaxf(runmax, tmax);
        float alpha = __expf(runmax - nmax);
        float psum = 0.f;
        #pragma unroll
        for (int nt = 0; nt < 4; ++nt) {
            short4 ev;
            #pragma unroll
            for (int r = 0; r < 4; ++r) {
                float e = __expf(sacc[nt][r] - nmax);
                psum += e;
                ((short*)&ev)[r] = f2bs(e);
            }
            int chunk = nt * 2 + (quad >> 1);
            *(short4*)&sTl[swz64(ms + l16, chunk) + (quad & 1) * 4] = ev;   // beta^T[m][n]
        }
        psum += __shfl_xor(psum, 16);
        psum += __shfl_xor(psum, 32);
        runsum = runsum * alpha + psum;
        runmax = nmax;

        // o-phase: o[c][m] += hh[c][n] * beta[n][m] ; wave reads only its own sTl rows
        #pragma unroll
        for (int ct = 0; ct < 8; ++ct) oacc[ct] = oacc[ct] * alpha;
        #pragma unroll
        for (int kk = 0; kk < 2; ++kk) {
            bf16x8 bs = *(const bf16x8*)&sTl[swz64(ms + l16, kk * 4 + quad)];
            #pragma unroll
            for (int ct = 0; ct < 8; ++ct) {
                bf16x8 ah = *(const bf16x8*)&hhl[swz64(ct * 16 + l16, kk * 4 + quad)];
                oacc[ct] = __builtin_amdgcn_mfma_f32_16x16x32_bf16(ah, bs, oacc[ct], 0, 0, 0);
            }
        }
    }

    // epilogue: obuf[b][m][c] bf16 (K-contiguous for conv4 B-frags)
    float inv = 1.0f / runsum;
    int m = m0 + ms + l16;
    #pragma unroll
    for (int ct = 0; ct < 8; ++ct) {
        short4 ov;
        #pragma unroll
        for (int r = 0; r < 4; ++r) ((short*)&ov)[r] = f2bs(oacc[ct][r] * inv);
        *(short4*)(obuf + ((size_t)bz * HW + m) * 128 + ct * 16 + quad * 4) = ov;
    }
}

// ---------------------------------------------------------------------------
// Kernel D: conv4 (256 oc <- 128 c) + BN + gamma*y + x, MFMA. One block = all
// 256 oc x 64 p for one batch (obuf tile read once). fp32 out.
// ---------------------------------------------------------------------------
__global__ __launch_bounds__(256) void conv4_mfma(
    const short* __restrict__ obuf,
    const float* __restrict__ x,
    const float* __restrict__ w4, const float* __restrict__ b4, const float* __restrict__ s4,
    const float* __restrict__ t4, const float* __restrict__ m4, const float* __restrict__ v4,
    const float* __restrict__ gamma, float* __restrict__ out)
{
    __shared__ __align__(16) short Wl[256 * 64];
    __shared__ __align__(16) short Xl[64 * 64];
    __shared__ float alB[256], beB[256];

    const int t = threadIdx.x;
    const int lane = t & 63, wv = t >> 6;
    const int quad = lane >> 4, l16 = lane & 15;
    const int bz = blockIdx.y;
    const int pBase = blockIdx.x * 64;

    {
        float al = s4[t] * rsqrtf(v4[t] + EPS);
        alB[t] = al; beB[t] = (b4[t] - m4[t]) * al + t4[t];
    }

    const f32x4 fzero = {0.f, 0.f, 0.f, 0.f};
    f32x4 acc[4][4];
    #pragma unroll
    for (int i = 0; i < 4; ++i)
        #pragma unroll
        for (int j = 0; j < 4; ++j) acc[i][j] = fzero;

    for (int k0 = 0; k0 < 128; k0 += 64) {
        // stage W4 (256 oc x 64 k)
        #pragma unroll
        for (int i = 0; i < 4; ++i) {
            int oc = i * 64 + (t >> 2);
            int kb = (t & 3) * 16;
            const float* wp = w4 + oc * 128 + k0 + kb;
            float4 a = *(const float4*)(wp);
            float4 b = *(const float4*)(wp + 4);
            float4 c = *(const float4*)(wp + 8);
            float4 d = *(const float4*)(wp + 12);
            bf16x8 lo, hi;
            lo[0]=f2bs(a.x); lo[1]=f2bs(a.y); lo[2]=f2bs(a.z); lo[3]=f2bs(a.w);
            lo[4]=f2bs(b.x); lo[5]=f2bs(b.y); lo[6]=f2bs(b.z); lo[7]=f2bs(b.w);
            hi[0]=f2bs(c.x); hi[1]=f2bs(c.y); hi[2]=f2bs(c.z); hi[3]=f2bs(c.w);
            hi[4]=f2bs(d.x); hi[5]=f2bs(d.y); hi[6]=f2bs(d.z); hi[7]=f2bs(d.w);
            *(bf16x8*)&Wl[swz64(oc, (kb >> 3))]     = lo;
            *(bf16x8*)&Wl[swz64(oc, (kb >> 3) + 1)] = hi;
        }
        // stage obuf tile [64 p][64 c] — already B-frag friendly ([p][c], contiguous c)
        {
            int pp = t >> 2, cb = (t & 3) * 16;
            const short* op = obuf + ((size_t)bz * HW + pBase + pp) * 128 + k0 + cb;
            bf16x8 lo = *(const bf16x8*)op;
            bf16x8 hi = *(const bf16x8*)(op + 8);
            *(bf16x8*)&Xl[swz64(pp, cb >> 3)]       = lo;
            *(bf16x8*)&Xl[swz64(pp, (cb >> 3) + 1)] = hi;
        }
        __syncthreads();
        #pragma unroll
        for (int kk = 0; kk < 2; ++kk) {
            bf16x8 bfr[4];
            #pragma unroll
            for (int pt = 0; pt < 4; ++pt)
                bfr[pt] = *(const bf16x8*)&Xl[swz64(pt * 16 + l16, kk * 4 + quad)];
            #pragma unroll
            for (int ot = 0; ot < 4; ++ot) {
                bf16x8 af = *(const bf16x8*)&Wl[swz64(wv * 64 + ot * 16 + l16, kk * 4 + quad)];
                #pragma unroll
                for (int pt = 0; pt < 4; ++pt)
                    acc[ot][pt] = __builtin_amdgcn_mfma_f32_16x16x32_bf16(af, bfr[pt], acc[ot][pt], 0, 0, 0);
            }
        }
        __syncthreads();
    }

    float gm = gamma[0];
    #pragma unroll
    for (int ot = 0; ot < 4; ++ot) {
        #pragma unroll
        for (int r = 0; r < 4; ++r) {
            int oc = wv * 64 + ot * 16 + quad * 4 + r;
            float al = alB[oc], be = beB[oc];
            #pragma unroll
            for (int pt = 0; pt < 4; ++pt) {
                int p = pBase + pt * 16 + l16;
                float y  = acc[ot][pt][r] * al + be;
                float xo = x[((size_t)bz * 256 + oc) * HW + p];
                out[((size_t)bz * 256 + oc) * HW + p] = gm * y + xo;
            }
        }
    }
}

extern "C" void kernel_launch(void* const* d_in, const int* in_sizes, int n_in,
                              void* d_out, int out_size, void* d_ws, size_t ws_size,
                              hipStream_t stream)
{
    const float* x  = (const float*)d_in[0];
    const float* w1 = (const float*)d_in[1];
    const float* b1 = (const float*)d_in[2];
    const float* s1 = (const float*)d_in[3];
    const float* t1 = (const float*)d_in[4];
    const float* m1 = (const float*)d_in[5];
    const float* v1 = (const float*)d_in[6];
    const float* w2 = (const float*)d_in[7];
    const float* b2 = (const float*)d_in[8];
    const float* s2 = (const float*)d_in[9];
    const float* t2 = (const float*)d_in[10];
    const float* m2 = (const float*)d_in[11];
    const float* v2 = (const float*)d_in[12];
    const float* w3 = (const float*)d_in[13];
    const float* b3 = (const float*)d_in[14];
    const float* s3 = (const float*)d_in[15];
    const float* t3 = (const float*)d_in[16];
    const float* m3 = (const float*)d_in[17];
    const float* v3 = (const float*)d_in[18];
    const float* w4 = (const float*)d_in[19];
    const float* b4 = (const float*)d_in[20];
    const float* s4 = (const float*)d_in[21];
    const float* t4 = (const float*)d_in[22];
    const float* m4 = (const float*)d_in[23];
    const float* v4 = (const float*)d_in[24];
    const float* gm = (const float*)d_in[25];
    float* out = (float*)d_out;

    short* y192  = (short*)d_ws;                     // 8*192*4096 bf16
    short* fbuf  = y192  + (size_t)8 * 192 * 4096;   // 8*32*1024
    short* hhbuf = fbuf  + (size_t)8 * 32 * 1024;    // 8*128*1024
    short* obuf  = hhbuf + (size_t)8 * 128 * 1024;   // 8*4096*128

    conv123_mfma<<<dim3(64, 8), 256, 0, stream>>>(
        x, w1, b1, s1, t1, m1, v1, w2, b2, s2, t2, m2, v2, w3, b3, s3, t3, m3, v3, y192);
    pool_kernel<<<dim3(5120), 256, 0, stream>>>(y192, fbuf, hhbuf);
    attn_mfma<<<dim3(64, 8), 256, 0, stream>>>(y192, fbuf, hhbuf, obuf);
    conv4_mfma<<<dim3(64, 8), 256, 0, stream>>>(
        obuf, x, w4, b4, s4, t4, m4, v4, gm, out);
}

// Round 4
// 173.889 us; speedup vs baseline: 2.7368x; 1.0621x over previous
//
#include <hip/hip_runtime.h>
#include <hip/hip_bf16.h>

#define HW   4096
#define HW4  1024
#define EPS  1e-5f

typedef __attribute__((ext_vector_type(8))) short bf16x8;   // 8 bf16 (4 VGPRs)
typedef __attribute__((ext_vector_type(4))) float f32x4;    // MFMA C/D

__device__ __forceinline__ short f2bs(float f) {            // fp32 -> bf16 bits (RNE)
    union { float f; unsigned u; } v; v.f = f;
    unsigned r = v.u + 0x7FFFu + ((v.u >> 16) & 1u);
    return (short)(r >> 16);
}
// XOR-swizzled LDS layouts (16B chunks permuted by row). Row strides 64/32/128 shorts.
__device__ __forceinline__ int swz64(int r, int c)  { return (r << 6) + ((c ^ (r & 7))  << 3); }
__device__ __forceinline__ int swz32(int r, int c)  { return (r << 5) + ((c ^ (r & 3))  << 3); }
__device__ __forceinline__ int swz128(int r, int c) { return (r << 7) + ((c ^ (r & 15)) << 3); }

// ---------------------------------------------------------------------------
// Kernel 1: conv1x1+BN+ReLU for branches 1-3, with 2x2 maxpool fused in
// registers. Block = (64 oc-tile, 128 p = one row-pair, batch). Outputs:
//   g  -> gbuf [8][32][4096]   (branch2, unpooled)
//   f  -> fbuf [8][32][1024]   (branch1, pooled)
//   hh -> hhbuf[8][128][1024]  (branch3, pooled)
// ---------------------------------------------------------------------------
__global__ __launch_bounds__(256) void conv123pool(
    const float* __restrict__ x,
    const float* __restrict__ w1, const float* __restrict__ b1, const float* __restrict__ s1,
    const float* __restrict__ t1, const float* __restrict__ m1, const float* __restrict__ v1,
    const float* __restrict__ w2, const float* __restrict__ b2, const float* __restrict__ s2,
    const float* __restrict__ t2, const float* __restrict__ m2, const float* __restrict__ v2,
    const float* __restrict__ w3, const float* __restrict__ b3, const float* __restrict__ s3,
    const float* __restrict__ t3, const float* __restrict__ m3, const float* __restrict__ v3,
    short* __restrict__ gbuf, short* __restrict__ fbuf, short* __restrict__ hhbuf)
{
    __shared__ __align__(16) short Wl[64 * 64];    // [oc][k] swz64
    __shared__ __align__(16) short Xl[128 * 64];   // [p][k]  swz64
    __shared__ float alB[64], beB[64];

    const int t = threadIdx.x;
    const int lane = t & 63, wv = t >> 6;
    const int quad = lane >> 4, l16 = lane & 15;
    const int ptile = blockIdx.x;     // 0..31 (row pair)
    const int octile = blockIdx.y;    // 0..2
    const int bz = blockIdx.z;
    const int pBase = ptile * 128;

    if (t < 64) {
        int j = octile * 64 + t;
        float pb, ps, ptv, pm, pv;
        if (j < 32)      { pb = b1[j]; ps = s1[j]; ptv = t1[j]; pm = m1[j]; pv = v1[j]; }
        else if (j < 64) { int c = j - 32; pb = b2[c]; ps = s2[c]; ptv = t2[c]; pm = m2[c]; pv = v2[c]; }
        else             { int c = j - 64; pb = b3[c]; ps = s3[c]; ptv = t3[c]; pm = m3[c]; pv = v3[c]; }
        float al = ps * rsqrtf(pv + EPS);
        alB[t] = al; beB[t] = (pb - pm) * al + ptv;
    }

    const f32x4 fzero = {0.f, 0.f, 0.f, 0.f};
    f32x4 acc[8];
    #pragma unroll
    for (int i = 0; i < 8; ++i) acc[i] = fzero;

    const int woc = t >> 2, wkb = (t & 3) * 16;    // W staging: thread -> oc row, 16-k slice
    const int xp  = t & 127, xk8 = t >> 7;         // X staging: thread -> p, 32-k half

    for (int k0 = 0; k0 < 256; k0 += 64) {
        // stage W chunk (64 oc x 64 k), fp32 -> bf16
        {
            int j = octile * 64 + woc;
            const float* wp = (j < 32) ? (w1 + j * 256)
                            : (j < 64) ? (w2 + (j - 32) * 256)
                                       : (w3 + (j - 64) * 256);
            wp += k0 + wkb;
            float4 a = *(const float4*)(wp);
            float4 b = *(const float4*)(wp + 4);
            float4 c = *(const float4*)(wp + 8);
            float4 d = *(const float4*)(wp + 12);
            bf16x8 lo, hi;
            lo[0]=f2bs(a.x); lo[1]=f2bs(a.y); lo[2]=f2bs(a.z); lo[3]=f2bs(a.w);
            lo[4]=f2bs(b.x); lo[5]=f2bs(b.y); lo[6]=f2bs(b.z); lo[7]=f2bs(b.w);
            hi[0]=f2bs(c.x); hi[1]=f2bs(c.y); hi[2]=f2bs(c.z); hi[3]=f2bs(c.w);
            hi[4]=f2bs(d.x); hi[5]=f2bs(d.y); hi[6]=f2bs(d.z); hi[7]=f2bs(d.w);
            *(bf16x8*)&Wl[swz64(woc, (wkb >> 3))]     = lo;
            *(bf16x8*)&Wl[swz64(woc, (wkb >> 3) + 1)] = hi;
        }
        // stage X transposed: Xl[p][k], 32 k values per thread
        {
            const float* xp0 = x + ((size_t)bz * 256 + k0 + xk8 * 32) * HW + pBase + xp;
            float fv[32];
            #pragma unroll
            for (int i = 0; i < 32; ++i) fv[i] = xp0[(size_t)i * HW];
            #pragma unroll
            for (int c = 0; c < 4; ++c) {
                bf16x8 v;
                #pragma unroll
                for (int jj = 0; jj < 8; ++jj) v[jj] = f2bs(fv[c * 8 + jj]);
                *(bf16x8*)&Xl[swz64(xp, xk8 * 4 + c)] = v;
            }
        }
        __syncthreads();
        #pragma unroll
        for (int kk = 0; kk < 2; ++kk) {
            bf16x8 afr = *(const bf16x8*)&Wl[swz64(wv * 16 + l16, kk * 4 + quad)];
            #pragma unroll
            for (int pt = 0; pt < 8; ++pt) {
                bf16x8 bfr = *(const bf16x8*)&Xl[swz64(pt * 16 + l16, kk * 4 + quad)];
                acc[pt] = __builtin_amdgcn_mfma_f32_16x16x32_bf16(afr, bfr, acc[pt], 0, 0, 0);
            }
        }
        __syncthreads();
    }

    // epilogue: BN+ReLU, then g-store or 2x2 pool (vert: pt vs pt+4; horz: shfl_xor 1)
    const bool isG = (octile == 0) && (wv >= 2);   // wave-uniform
    #pragma unroll
    for (int r = 0; r < 4; ++r) {
        int ocl = wv * 16 + quad * 4 + r;
        float al = alB[ocl], be = beB[ocl];
        float y[8];
        #pragma unroll
        for (int pt = 0; pt < 8; ++pt) y[pt] = fmaxf(acc[pt][r] * al + be, 0.f);
        int j = octile * 64 + ocl;
        if (isG) {
            #pragma unroll
            for (int pt = 0; pt < 8; ++pt)
                gbuf[((size_t)bz * 32 + (j - 32)) * HW + pBase + pt * 16 + l16] = f2bs(y[pt]);
        } else {
            #pragma unroll
            for (int pt = 0; pt < 4; ++pt) {
                float v  = fmaxf(y[pt], y[pt + 4]);      // vertical pair (rows 2r,2r+1)
                float po = fmaxf(v, __shfl_xor(v, 1));   // horizontal pair (w even/odd)
                if ((l16 & 1) == 0) {
                    int n = ptile * 32 + ((pt * 16 + l16) >> 1);
                    if (j < 32) fbuf[((size_t)bz * 32 + j) * HW4 + n] = f2bs(po);
                    else        hhbuf[((size_t)bz * 128 + (j - 64)) * HW4 + n] = f2bs(po);
                }
            }
        }
    }
}

// ---------------------------------------------------------------------------
// Kernel 2: fused flash attention + conv4 + BN + residual. Block = (batch,
// 64-m tile). Attn phase as before (wave owns 16-m strip, online softmax,
// o in AGPRs). Then o -> LDS (reusing dead attn LDS), conv4 MFMA
// (256 oc <- 128 c), epilogue out = gamma*(BN(conv)) + x. fp32 out.
// LDS peak 48KB + 2KB stats -> 3 blocks/CU.
// ---------------------------------------------------------------------------
__global__ __launch_bounds__(256) void attn_conv4(
    const short* __restrict__ gbuf,
    const short* __restrict__ fbuf,
    const short* __restrict__ hhbuf,
    const float* __restrict__ x,
    const float* __restrict__ w4, const float* __restrict__ b4, const float* __restrict__ s4,
    const float* __restrict__ t4, const float* __restrict__ m4, const float* __restrict__ v4,
    const float* __restrict__ gamma, float* __restrict__ out)
{
    __shared__ __align__(16) short smem[24576];    // 48 KB
    __shared__ float alB4[256], beB4[256];
    short* gTl = smem;            // [64m][32k]  swz32, 2048 shorts
    short* fTl = smem + 2048;     // [64n][32k]  swz32, 2048
    short* sTl = smem + 4096;     // [64m][64n]  swz64, 4096 (beta^T)
    short* hhl = smem + 8192;     // [128c][64n] swz64, 8192
    short* o_l = smem;            // [64m][128c] swz128, 8192 (phase 2, over gTl/fTl/sTl)
    short* Wl4 = smem + 8192;     // [256oc][64k] swz64, 16384 (phase 2, over hhl+)

    const int t = threadIdx.x;
    const int lane = t & 63, wv = t >> 6;
    const int quad = lane >> 4, l16 = lane & 15;
    const int bz = blockIdx.y;
    const int m0 = blockIdx.x * 64;
    const int ms = wv * 16;
    const f32x4 fzero = {0.f, 0.f, 0.f, 0.f};

    {   // conv4 BN constants (one oc per thread)
        float al = s4[t] * rsqrtf(v4[t] + EPS);
        alB4[t] = al; beB4[t] = (b4[t] - m4[t]) * al + t4[t];
    }

    // stage g^T once: gTl[m][k]
    {
        int mm = t & 63, k8 = t >> 6;
        bf16x8 v;
        #pragma unroll
        for (int j = 0; j < 8; ++j)
            v[j] = gbuf[((size_t)bz * 32 + k8 * 8 + j) * HW + m0 + mm];
        *(bf16x8*)&gTl[swz32(mm, k8)] = v;
    }
    __syncthreads();
    bf16x8 bg = *(const bf16x8*)&gTl[swz32(ms + l16, quad)];   // loop-invariant B-frag

    float runmax = -1e30f, runsum = 0.f;
    f32x4 oacc[8];
    #pragma unroll
    for (int i = 0; i < 8; ++i) oacc[i] = fzero;

    for (int n0 = 0; n0 < 1024; n0 += 64) {
        __syncthreads();   // prior-iter readers of fTl/hhl done
        // stage f^T: fTl[n][k]
        {
            int nn = t & 63, k8 = t >> 6;
            bf16x8 v;
            #pragma unroll
            for (int j = 0; j < 8; ++j)
                v[j] = fbuf[((size_t)bz * 32 + k8 * 8 + j) * HW4 + n0 + nn];
            *(bf16x8*)&fTl[swz32(nn, k8)] = v;
        }
        // stage hh: hhl[c][n]
        {
            int c0 = t >> 3, nc = t & 7;
            #pragma unroll
            for (int i = 0; i < 4; ++i) {
                int c = i * 32 + c0;
                bf16x8 v = *(const bf16x8*)(hhbuf + ((size_t)bz * 128 + c) * HW4 + n0 + nc * 8);
                *(bf16x8*)&hhl[swz64(c, nc)] = v;
            }
        }
        __syncthreads();

        // s-phase: s[n][m] for wave's 16-m strip, 4 n-tiles
        f32x4 sacc[4];
        #pragma unroll
        for (int nt = 0; nt < 4; ++nt) {
            bf16x8 af = *(const bf16x8*)&fTl[swz32(nt * 16 + l16, quad)];
            sacc[nt] = __builtin_amdgcn_mfma_f32_16x16x32_bf16(af, bg, fzero, 0, 0, 0);
        }

        // online softmax over n (per-lane m stats; reduce across quads)
        float tmax = -1e30f;
        #pragma unroll
        for (int nt = 0; nt < 4; ++nt)
            #pragma unroll
            for (int r = 0; r < 4; ++r) tmax = fmaxf(tmax, sacc[nt][r]);
        tmax = fmaxf(tmax, __shfl_xor(tmax, 16));
        tmax = fmaxf(tmax, __shfl_xor(tmax, 32));
        float nmax  = fmaxf(runmax, tmax);
        float alpha = __expf(runmax - nmax);
        float psum = 0.f;
        #pragma unroll
        for (int nt = 0; nt < 4; ++nt) {
            short4 ev;
            #pragma unroll
            for (int r = 0; r < 4; ++r) {
                float e = __expf(sacc[nt][r] - nmax);
                psum += e;
                ((short*)&ev)[r] = f2bs(e);
            }
            int chunk = nt * 2 + (quad >> 1);
            *(short4*)&sTl[swz64(ms + l16, chunk) + (quad & 1) * 4] = ev;   // beta^T[m][n]
        }
        psum += __shfl_xor(psum, 16);
        psum += __shfl_xor(psum, 32);
        runsum = runsum * alpha + psum;
        runmax = nmax;

        // o-phase: o[c][m] += hh[c][n] * beta[n][m]; wave reads own sTl rows only
        #pragma unroll
        for (int ct = 0; ct < 8; ++ct) oacc[ct] = oacc[ct] * alpha;
        #pragma unroll
        for (int kk = 0; kk < 2; ++kk) {
            bf16x8 bs = *(const bf16x8*)&sTl[swz64(ms + l16, kk * 4 + quad)];
            #pragma unroll
            for (int ct = 0; ct < 8; ++ct) {
                bf16x8 ah = *(const bf16x8*)&hhl[swz64(ct * 16 + l16, kk * 4 + quad)];
                oacc[ct] = __builtin_amdgcn_mfma_f32_16x16x32_bf16(ah, bs, oacc[ct], 0, 0, 0);
            }
        }
    }
    __syncthreads();   // all attn LDS reads complete

    // write normalized o^T to LDS: o_l[m][c] (overwrites gTl/fTl/sTl)
    {
        float inv = 1.0f / runsum;
        int m = ms + l16;
        #pragma unroll
        for (int ct = 0; ct < 8; ++ct) {
            short4 ov;
            #pragma unroll
            for (int r = 0; r < 4; ++r) ((short*)&ov)[r] = f2bs(oacc[ct][r] * inv);
            *(short4*)&o_l[swz128(m, ct * 2 + (quad >> 1)) + (quad & 1) * 4] = ov;
        }
    }
    __syncthreads();   // o_l ready; hhl dead -> Wl4 may overwrite

    // conv4: out[oc][m] = W4(256x128) . o(128x64m)
    f32x4 acc4[4][4];
    #pragma unroll
    for (int i = 0; i < 4; ++i)
        #pragma unroll
        for (int j = 0; j < 4; ++j) acc4[i][j] = fzero;

    for (int c0 = 0; c0 < 128; c0 += 64) {
        #pragma unroll
        for (int i = 0; i < 4; ++i) {
            int oc = i * 64 + (t >> 2);
            int kb = (t & 3) * 16;
            const float* wp = w4 + oc * 128 + c0 + kb;
            float4 a = *(const float4*)(wp);
            float4 b = *(const float4*)(wp + 4);
            float4 c = *(const float4*)(wp + 8);
            float4 d = *(const float4*)(wp + 12);
            bf16x8 lo, hi;
            lo[0]=f2bs(a.x); lo[1]=f2bs(a.y); lo[2]=f2bs(a.z); lo[3]=f2bs(a.w);
            lo[4]=f2bs(b.x); lo[5]=f2bs(b.y); lo[6]=f2bs(b.z); lo[7]=f2bs(b.w);
            hi[0]=f2bs(c.x); hi[1]=f2bs(c.y); hi[2]=f2bs(c.z); hi[3]=f2bs(c.w);
            hi[4]=f2bs(d.x); hi[5]=f2bs(d.y); hi[6]=f2bs(d.z); hi[7]=f2bs(d.w);
            *(bf16x8*)&Wl4[swz64(oc, (kb >> 3))]     = lo;
            *(bf16x8*)&Wl4[swz64(oc, (kb >> 3) + 1)] = hi;
        }
        __syncthreads();
        #pragma unroll
        for (int kk = 0; kk < 2; ++kk) {
            bf16x8 bfr[4];
            #pragma unroll
            for (int mt = 0; mt < 4; ++mt)
                bfr[mt] = *(const bf16x8*)&o_l[swz128(mt * 16 + l16, (c0 >> 3) + kk * 4 + quad)];
            #pragma unroll
            for (int ot = 0; ot < 4; ++ot) {
                bf16x8 afr = *(const bf16x8*)&Wl4[swz64(wv * 64 + ot * 16 + l16, kk * 4 + quad)];
                #pragma unroll
                for (int mt = 0; mt < 4; ++mt)
                    acc4[ot][mt] = __builtin_amdgcn_mfma_f32_16x16x32_bf16(afr, bfr[mt], acc4[ot][mt], 0, 0, 0);
            }
        }
        __syncthreads();
    }

    float gm = gamma[0];
    #pragma unroll
    for (int ot = 0; ot < 4; ++ot) {
        #pragma unroll
        for (int r = 0; r < 4; ++r) {
            int oc = wv * 64 + ot * 16 + quad * 4 + r;
            float al = alB4[oc], be = beB4[oc];
            #pragma unroll
            for (int mt = 0; mt < 4; ++mt) {
                int p = m0 + mt * 16 + l16;
                float y  = acc4[ot][mt][r] * al + be;
                float xo = x[((size_t)bz * 256 + oc) * HW + p];
                out[((size_t)bz * 256 + oc) * HW + p] = gm * y + xo;
            }
        }
    }
}

extern "C" void kernel_launch(void* const* d_in, const int* in_sizes, int n_in,
                              void* d_out, int out_size, void* d_ws, size_t ws_size,
                              hipStream_t stream)
{
    const float* x  = (const float*)d_in[0];
    const float* w1 = (const float*)d_in[1];
    const float* b1 = (const float*)d_in[2];
    const float* s1 = (const float*)d_in[3];
    const float* t1 = (const float*)d_in[4];
    const float* m1 = (const float*)d_in[5];
    const float* v1 = (const float*)d_in[6];
    const float* w2 = (const float*)d_in[7];
    const float* b2 = (const float*)d_in[8];
    const float* s2 = (const float*)d_in[9];
    const float* t2 = (const float*)d_in[10];
    const float* m2 = (const float*)d_in[11];
    const float* v2 = (const float*)d_in[12];
    const float* w3 = (const float*)d_in[13];
    const float* b3 = (const float*)d_in[14];
    const float* s3 = (const float*)d_in[15];
    const float* t3 = (const float*)d_in[16];
    const float* m3 = (const float*)d_in[17];
    const float* v3 = (const float*)d_in[18];
    const float* w4 = (const float*)d_in[19];
    const float* b4 = (const float*)d_in[20];
    const float* s4 = (const float*)d_in[21];
    const float* t4 = (const float*)d_in[22];
    const float* m4 = (const float*)d_in[23];
    const float* v4 = (const float*)d_in[24];
    const float* gm = (const float*)d_in[25];
    float* out = (float*)d_out;

    short* gbuf  = (short*)d_ws;                     // 8*32*4096 bf16 (2 MB)
    short* fbuf  = gbuf  + (size_t)8 * 32 * 4096;    // 8*32*1024  (0.5 MB)
    short* hhbuf = fbuf  + (size_t)8 * 32 * 1024;    // 8*128*1024 (2 MB)

    conv123pool<<<dim3(32, 3, 8), 256, 0, stream>>>(
        x, w1, b1, s1, t1, m1, v1, w2, b2, s2, t2, m2, v2, w3, b3, s3, t3, m3, v3,
        gbuf, fbuf, hhbuf);
    attn_conv4<<<dim3(64, 8), 256, 0, stream>>>(
        gbuf, fbuf, hhbuf, x, w4, b4, s4, t4, m4, v4, gm, out);
}